// Round 2
// baseline (366.709 us; speedup 1.0000x reference)
//
#include <hip/hip_runtime.h>
#include <hip/hip_bf16.h>

// NeuS-style renderer sampling (all fp32, per reference):
//  inputs: ray_dirs (1,262144,3), cam_loc (1,3), t_rand (262144,64)
//  outputs (concat): new_samples (P,32,3), z_samples (P,32), weights (P,63)
// Kernel 1: global reduction of mean_si over hit rays -> ws[0..2].
// Kernel 2: one wave (64 lanes) per ray; lane j owns step j. Cross-step ops
// (cumprod/cumsum/searchsorted) are wave shuffles — no LDS, no spills.

static constexpr int NSTEPS = 64;

__global__ void ws_init_kernel(float* ws){
  int t = blockIdx.x * blockDim.x + threadIdx.x;
  if (t < 3) ws[t] = 0.0f;
}

// Pass 1: sum si0, si1, count over rays with under > 0.
__global__ __launch_bounds__(256) void si_reduce_kernel(
    const float* __restrict__ rd,
    const float* __restrict__ cam,
    float* __restrict__ ws, int P)
{
  int p = blockIdx.x * blockDim.x + threadIdx.x;
  float cx = cam[0], cy = cam[1], cz = cam[2];
  float c2m = cx*cx + cy*cy + cz*cz - 1.0f;   // |cam|^2 - R^2, R=1
  float s0 = 0.f, s1 = 0.f, cnt = 0.f;
  if (p < P){
    float dx = rd[3*p+0], dy = rd[3*p+1], dz = rd[3*p+2];
    float rcd = dx*cx + dy*cy + dz*cz;
    float under = rcd*rcd - c2m;
    if (under > 0.f){
      float sq = sqrtf(under);
      s0 = -sq - rcd; s1 = sq - rcd; cnt = 1.f;
    }
  }
  #pragma unroll
  for (int off = 32; off > 0; off >>= 1){
    s0  += __shfl_down(s0,  off, 64);
    s1  += __shfl_down(s1,  off, 64);
    cnt += __shfl_down(cnt, off, 64);
  }
  __shared__ float sh0[4], sh1[4], sh2[4];
  int w = threadIdx.x >> 6, lane = threadIdx.x & 63;
  if (lane == 0){ sh0[w] = s0; sh1[w] = s1; sh2[w] = cnt; }
  __syncthreads();
  if (threadIdx.x == 0){
    atomicAdd(&ws[0], sh0[0]+sh0[1]+sh0[2]+sh0[3]);
    atomicAdd(&ws[1], sh1[0]+sh1[1]+sh1[2]+sh1[3]);
    atomicAdd(&ws[2], sh2[0]+sh2[1]+sh2[2]+sh2[3]);
  }
}

// Pass 2: one wave per ray.
__global__ __launch_bounds__(256) void render_main_kernel(
    const float* __restrict__ rd,
    const float* __restrict__ cam,
    const float* __restrict__ tr,
    const float* __restrict__ ws,
    float* __restrict__ out, int P)
{
  const int lane = threadIdx.x & 63;
  const int p = blockIdx.x * (blockDim.x >> 6) + (threadIdx.x >> 6);
  if (p >= P) return;   // wave-uniform exit

  float cx = cam[0], cy = cam[1], cz = cam[2];
  float c2m = cx*cx + cy*cy + cz*cz - 1.0f;
  float dx = rd[3*p+0], dy = rd[3*p+1], dz = rd[3*p+2];
  float rcd = dx*cx + dy*cy + dz*cz;
  float under = rcd*rcd - c2m;
  float si0, si1;
  if (under > 0.f){
    float sq = sqrtf(under);
    si0 = -sq - rcd; si1 = sq - rcd;
  } else {
    float nh = fmaxf(ws[2], 1.0f);
    si0 = ws[0] / nh; si1 = ws[1] / nh;
  }
  float min_d = fmaxf(si0, 0.f), max_d = fmaxf(si1, 0.f);
  float range = max_d - min_d;
  float sdist = range * (1.0f / NSTEPS);      // (max-min)/64 per reference

  // steps[lane]
  float trand = tr[(size_t)p * NSTEPS + lane];
  float stepv = min_d + range * ((float)lane * (1.0f/63.0f)) + (trand - 0.5f) * sdist;

  // sdf + sigmoid at this step
  float px = cx + stepv*dx, py = cy + stepv*dy, pz = cz + stepv*dz;
  float sdf = sqrtf(px*px + py*py + pz*pz) - 0.5f;
  const float inv_s = 20.085536923187668f;    // exp(0.3*10)
  float c = 1.0f / (1.0f + __expf(-sdf * inv_s));

  // alpha[j] from c[j], c[j+1]  (j = 0..62)
  float cnext = __shfl_down(c, 1, 64);
  float alpha = 0.f;
  if (lane < 63){
    alpha = (c - cnext + 1e-8f) / (c + 1e-8f);
    alpha = fminf(fmaxf(alpha, 0.f), 1.0f);
  }

  // trans[j] = exclusive cumprod of (1 - alpha + 1e-7)
  float f = 1.0f - alpha + 1e-7f;
  float prod = f;
  #pragma unroll
  for (int off = 1; off < 64; off <<= 1){
    float o = __shfl_up(prod, off, 64);
    if (lane >= off) prod *= o;
  }
  float trans = __shfl_up(prod, 1, 64);
  if (lane == 0) trans = 1.0f;
  float wgt = alpha * trans;                  // weights[j], lane 63 -> 0

  // cdf: wp[j] = weights+1e-8 (j<63), 0 at lane 63; inclusive scan; cdf=ex/T
  float wp = (lane < 63) ? (wgt + 1e-8f) : 0.f;
  float s = wp;
  #pragma unroll
  for (int off = 1; off < 64; off <<= 1){
    float o = __shfl_up(s, off, 64);
    if (lane >= off) s += o;
  }
  float T  = __shfl(s, 63, 64);               // total
  float ex = __shfl_up(s, 1, 64);
  if (lane == 0) ex = 0.f;
  float cdf = ex / T;                         // cdf[0]=0 .. cdf[63]=1

  // searchsorted(cdf, u, 'right'): lane i (mod 32) handles sample i
  int i = lane & 31;
  float u = (float)(2*i + 1) * (1.0f / 64.0f);
  int pos = 0;
  #pragma unroll
  for (int st = 32; st > 0; st >>= 1){
    int idx = pos + st - 1; idx = idx > 63 ? 63 : idx;
    float cv = __shfl(cdf, idx, 64);          // all lanes participate
    if (cv <= u) pos += st;
  }
  int below = pos - 1; if (below < 0) below = 0;
  int above = pos < 63 ? pos : 63;
  float cdf_b = __shfl(cdf,  below, 64);
  float cdf_a = __shfl(cdf,  above, 64);
  float bin_b = __shfl(stepv, below, 64);
  float bin_a = __shfl(stepv, above, 64);
  float denom = cdf_a - cdf_b;
  if (denom < 1e-8f) denom = 1.0f;
  float t = (u - cdf_b) / denom;
  float z = bin_b + t * (bin_a - bin_b);

  // outputs
  const size_t P96  = (size_t)P * 96;         // new_samples elems
  const size_t P128 = (size_t)P * 128;        // + z_samples elems
  if (lane < 32){
    float nx = cx + z*dx, ny = cy + z*dy, nz = cz + z*dz;
    size_t base = (size_t)p * 96 + (size_t)lane * 3;
    out[base + 0] = nx;
    out[base + 1] = ny;
    out[base + 2] = nz;
    out[P96 + (size_t)p * 32 + lane] = z;
  }
  if (lane < 63){
    out[P128 + (size_t)p * 63 + lane] = wgt;
  }
}

extern "C" void kernel_launch(void* const* d_in, const int* in_sizes, int n_in,
                              void* d_out, int out_size, void* d_ws, size_t ws_size,
                              hipStream_t stream) {
  const float* rd  = (const float*)d_in[0];
  const float* cam = (const float*)d_in[1];
  const float* tr  = (const float*)d_in[2];
  float* out = (float*)d_out;
  float* ws  = (float*)d_ws;
  const int P = in_sizes[0] / 3;              // 262144 rays

  ws_init_kernel<<<1, 64, 0, stream>>>(ws);
  si_reduce_kernel<<<(P + 255) / 256, 256, 0, stream>>>(rd, cam, ws, P);
  const int raysPerBlock = 4;                 // 256 threads = 4 waves
  render_main_kernel<<<(P + raysPerBlock - 1) / raysPerBlock, 256, 0, stream>>>(
      rd, cam, tr, ws, out, P);
}